// Round 1
// baseline (275.287 us; speedup 1.0000x reference)
//
#include <hip/hip_runtime.h>

#define E_N 65536
#define D_N 256
#define T_N 9
#define TM  64
#define HPAD 256

// ws layout (float offsets)
#define OFF_C   0          // 9*256*256 = 589824
#define OFF_A   589824     // 14*256 = 3584
#define OFF_B   593408     // 4*256 = 1024
#define OFF_D2  594432     // 9*256 = 2304
#define OFF_CNT 596736     // 16 ints
#define OFF_IDX 596752     // 9*65536 ints
#define WS_NEED_BYTES ((size_t)(596752 + 589824) * 4)

__device__ __constant__ float SCALES_C[9][4] = {
  {1.f,    1e-6f, 1.f,  1.f},   // nmos
  {1.f,    1e-6f, 1.f,  1.f},   // pmos
  {1.f,    1.f,   1.f,  1.f},   // balun
  {1e3f,   1.f,   1.f,  1.f},   // resistor
  {1e-12f, 1.f,   1.f,  1.f},   // capacitor
  {1e-9f,  1.f,   1.f,  1.f},   // inductor
  {1.f,    1.f,   1.f,  1.f},   // vsource
  {1e-3f,  1e-3f, 1.f,  1.f},   // isource
  {1.f,    1.f,   1e9f, 1.f},   // port
};

// ---------------- bucketing: wave-aggregated atomic scatter ----------------
__global__ void bucket_kernel(const int* __restrict__ base_ids,
                              int* __restrict__ cnt, int* __restrict__ idx)
{
  int e = blockIdx.x * blockDim.x + threadIdx.x;   // E is exact multiple of 256
  int b = base_ids[e];
  int lane = threadIdx.x & 63;
  unsigned long long lanebit = 1ull << lane;
  #pragma unroll 1
  for (int t = 0; t < T_N; ++t) {
    unsigned long long m = __ballot(b == t);
    if (b == t) {
      int leader = __ffsll((unsigned long long)m) - 1;
      int c = __popcll(m);
      int base = 0;
      if (lane == leader) base = atomicAdd(&cnt[t], c);
      base = __shfl(base, leader);
      int pos = base + __popcll(m & (lanebit - 1ull));
      idx[t * E_N + pos] = e;
    }
  }
}

// ---------------- precompute C[t] = W2[t] @ Wf[512:768] ----------------
__global__ __launch_bounds__(256) void precompute_C(
    const float* __restrict__ W2, const float* __restrict__ Wf,
    float* __restrict__ C)
{
  int t  = blockIdx.y;
  int j0 = blockIdx.x * 8;
  int d  = threadIdx.x;
  __shared__ float w2s[8][256];
  for (int i = threadIdx.x; i < 8 * 256; i += 256)
    w2s[i >> 8][i & 255] = W2[t * 65536 + (j0 + (i >> 8)) * 256 + (i & 255)];
  __syncthreads();
  float acc[8] = {0.f,0.f,0.f,0.f,0.f,0.f,0.f,0.f};
  #pragma unroll 4
  for (int k = 0; k < 256; ++k) {
    float wv = Wf[(512 + k) * 256 + d];
    #pragma unroll
    for (int jj = 0; jj < 8; ++jj)
      acc[jj] = fmaf(w2s[jj][k], wv, acc[jj]);
  }
  #pragma unroll
  for (int jj = 0; jj < 8; ++jj)
    C[t * 65536 + (j0 + jj) * 256 + d] = acc[jj];
}

// -------- precompute A[type]=te@Wf0, B[src]=se@Wf1, D2b[t]=b2@Wf2+bf --------
__global__ __launch_bounds__(256) void precompute_ABD(
    const float* __restrict__ te, const float* __restrict__ se,
    const float* __restrict__ b2, const float* __restrict__ Wf,
    const float* __restrict__ bfv,
    float* __restrict__ Ab, float* __restrict__ Bb, float* __restrict__ D2b)
{
  int b = blockIdx.x;
  int d = threadIdx.x;
  float acc = 0.f;
  if (b < 14) {
    const float* em = te + b * 256;
    #pragma unroll 8
    for (int k = 0; k < 256; ++k) acc = fmaf(em[k], Wf[k * 256 + d], acc);
    Ab[b * 256 + d] = acc;
  } else if (b < 18) {
    const float* em = se + (b - 14) * 256;
    #pragma unroll 8
    for (int k = 0; k < 256; ++k) acc = fmaf(em[k], Wf[(256 + k) * 256 + d], acc);
    Bb[(b - 14) * 256 + d] = acc;
  } else {
    const float* em = b2 + (b - 18) * 256;
    #pragma unroll 8
    for (int k = 0; k < 256; ++k) acc = fmaf(em[k], Wf[(512 + k) * 256 + d], acc);
    D2b[(b - 18) * 256 + d] = acc + bfv[d];
  }
}

// ---------------- main grouped GEMM: out = relu(h @ C[t] + biases) ----------------
__global__ __launch_bounds__(256, 1) void edge_gemm(
    const int* __restrict__ cnt, const int* __restrict__ idx,
    const int* __restrict__ type_ids, const int* __restrict__ source_ids,
    const float* __restrict__ params,
    const float* __restrict__ W1, const float* __restrict__ b1,
    const float* __restrict__ C, const float* __restrict__ Ab,
    const float* __restrict__ Bb, const float* __restrict__ D2b,
    float* __restrict__ out)
{
  int t = blockIdx.y;
  int n = cnt[t];
  int m0blk = blockIdx.x * TM;
  if (m0blk >= n) return;

  __shared__ float  hT[TM][HPAD];   // 64 KB, [m][k]; writes by-lane-d conflict-free, reads wave-uniform
  __shared__ int    eidx[TM];
  __shared__ int    etyp[TM];
  __shared__ int    esrc[TM];
  __shared__ float4 xs[TM];

  int tid = threadIdx.x;
  if (tid < TM) {
    int m  = m0blk + tid;
    int mc = (m < n) ? m : (n - 1);
    int e  = idx[t * E_N + mc];
    eidx[tid] = e;
    etyp[tid] = type_ids[e];
    esrc[tid] = source_ids[e];
    float4 pr = *(const float4*)(params + (size_t)e * 4);
    float4 x;
    x.x = pr.x / SCALES_C[t][0];
    x.y = pr.y / SCALES_C[t][1];
    x.z = pr.z / SCALES_C[t][2];
    x.w = pr.w / SCALES_C[t][3];
    xs[tid] = x;
  }
  __syncthreads();

  // h[m][d] = relu(x[m] . W1[t][:,d] + b1[t][d]) for all 64 m, this thread's d
  {
    int d = tid;
    const float* W1t = W1 + t * 1024;
    float w0 = W1t[d], w1 = W1t[256 + d], w2 = W1t[512 + d], w3 = W1t[768 + d];
    float b1d = b1[t * 256 + d];
    #pragma unroll 4
    for (int m = 0; m < TM; ++m) {
      float4 x = xs[m];
      float h = fmaf(x.x, w0, fmaf(x.y, w1, fmaf(x.z, w2, fmaf(x.w, w3, b1d))));
      hT[m][d] = fmaxf(h, 0.f);
    }
  }
  __syncthreads();

  int dq = (tid & 63) << 2;   // 4 consecutive d per thread
  int mq = (tid >> 6) << 4;   // 16 m per thread (wave-uniform)
  float4 acc[16];
  #pragma unroll
  for (int i = 0; i < 16; ++i) acc[i] = make_float4(0.f, 0.f, 0.f, 0.f);

  const float* Ct = C + t * 65536;
  for (int k = 0; k < 256; k += 4) {
    float4 c0 = *(const float4*)(Ct + (k + 0) * 256 + dq);
    float4 c1 = *(const float4*)(Ct + (k + 1) * 256 + dq);
    float4 c2 = *(const float4*)(Ct + (k + 2) * 256 + dq);
    float4 c3 = *(const float4*)(Ct + (k + 3) * 256 + dq);
    #pragma unroll
    for (int mm = 0; mm < 16; ++mm) {
      float4 hv = *(const float4*)(&hT[mq + mm][k]);   // wave-uniform broadcast
      acc[mm].x = fmaf(hv.x, c0.x, fmaf(hv.y, c1.x, fmaf(hv.z, c2.x, fmaf(hv.w, c3.x, acc[mm].x))));
      acc[mm].y = fmaf(hv.x, c0.y, fmaf(hv.y, c1.y, fmaf(hv.z, c2.y, fmaf(hv.w, c3.y, acc[mm].y))));
      acc[mm].z = fmaf(hv.x, c0.z, fmaf(hv.y, c1.z, fmaf(hv.z, c2.z, fmaf(hv.w, c3.z, acc[mm].z))));
      acc[mm].w = fmaf(hv.x, c0.w, fmaf(hv.y, c1.w, fmaf(hv.z, c2.w, fmaf(hv.w, c3.w, acc[mm].w))));
    }
  }

  float4 dbv = *(const float4*)(D2b + t * 256 + dq);
  #pragma unroll
  for (int mm = 0; mm < 16; ++mm) {
    int m = m0blk + mq + mm;
    if (m >= n) break;
    int e = eidx[mq + mm];
    float4 av = *(const float4*)(Ab + etyp[mq + mm] * 256 + dq);
    float4 bv = *(const float4*)(Bb + esrc[mq + mm] * 256 + dq);
    float4 a = acc[mm];
    float4 r;
    r.x = fmaxf(a.x + av.x + bv.x + dbv.x, 0.f);
    r.y = fmaxf(a.y + av.y + bv.y + dbv.y, 0.f);
    r.z = fmaxf(a.z + av.z + bv.z + dbv.z, 0.f);
    r.w = fmaxf(a.w + av.w + bv.w + dbv.w, 0.f);
    *(float4*)(out + (size_t)e * 256 + dq) = r;
  }
}

extern "C" void kernel_launch(void* const* d_in, const int* in_sizes, int n_in,
                              void* d_out, int out_size, void* d_ws, size_t ws_size,
                              hipStream_t stream) {
  const int*   type_ids   = (const int*)  d_in[0];
  const int*   source_ids = (const int*)  d_in[1];
  const int*   base_ids   = (const int*)  d_in[2];
  const float* params     = (const float*)d_in[3];
  const float* type_embed = (const float*)d_in[4];
  const float* src_embed  = (const float*)d_in[5];
  const float* W1         = (const float*)d_in[6];
  const float* b1         = (const float*)d_in[7];
  const float* W2         = (const float*)d_in[8];
  const float* b2         = (const float*)d_in[9];
  const float* Wf         = (const float*)d_in[10];
  const float* bfv        = (const float*)d_in[11];
  float* out = (float*)d_out;

  if (ws_size < WS_NEED_BYTES) return;  // loud failure rather than corruption

  float* wsf  = (float*)d_ws;
  float* C    = wsf + OFF_C;
  float* Ab   = wsf + OFF_A;
  float* Bb   = wsf + OFF_B;
  float* D2b  = wsf + OFF_D2;
  int*   cnt  = (int*)(wsf + OFF_CNT);
  int*   idx  = (int*)(wsf + OFF_IDX);

  hipMemsetAsync(cnt, 0, 16 * sizeof(int), stream);
  bucket_kernel<<<E_N / 256, 256, 0, stream>>>(base_ids, cnt, idx);
  precompute_C<<<dim3(32, T_N), 256, 0, stream>>>(W2, Wf, C);
  precompute_ABD<<<27, 256, 0, stream>>>(type_embed, src_embed, b2, Wf, bfv,
                                         Ab, Bb, D2b);
  edge_gemm<<<dim3(E_N / TM, T_N), 256, 0, stream>>>(
      cnt, idx, type_ids, source_ids, params, W1, b1, C, Ab, Bb, D2b, out);
}

// Round 2
// 88.493 us; speedup vs baseline: 3.1108x; 3.1108x over previous
//
#include <hip/hip_runtime.h>

#define E_N 65536
#define D_N 256
#define T_N 9

typedef __bf16 bf16x8 __attribute__((ext_vector_type(8)));
typedef float f32x4 __attribute__((ext_vector_type(4)));
typedef unsigned short ushort8 __attribute__((ext_vector_type(8)));
union U8 { ushort8 u; bf16x8 b; };

// ---------------- ws layout (float offsets) ----------------
#define OFF_CB   0                    // 9*256*256 ushort = 294912 floats (bf16 packed C)
#define OFF_ABC  294912               // 56*256 floats
#define OFF_D2   309248               // 9*256 floats
#define OFF_WH   311552               // 9*1024 ints (per-wave histograms, [t][gw])
#define OFF_WB   320768               // 9*1024 ints (per-wave bases)
#define OFF_IDX  329984               // 9*65536 ints
#define WS_NEED_BYTES ((size_t)(329984 + 589824) * 4)

__device__ __constant__ float SCALES_C[9][4] = {
  {1.f,    1e-6f, 1.f,  1.f},
  {1.f,    1e-6f, 1.f,  1.f},
  {1.f,    1.f,   1.f,  1.f},
  {1e3f,   1.f,   1.f,  1.f},
  {1e-12f, 1.f,   1.f,  1.f},
  {1e-9f,  1.f,   1.f,  1.f},
  {1.f,    1.f,   1.f,  1.f},
  {1e-3f,  1e-3f, 1.f,  1.f},
  {1.f,    1.f,   1e9f, 1.f},
};

__device__ inline unsigned short f2bf(float f) {
  unsigned int u = __float_as_uint(f);
  unsigned int r = (u + 0x7FFFu + ((u >> 16) & 1u)) >> 16;
  return (unsigned short)r;
}

// ---------------- bucketing: hist -> prefix -> scatter (no atomics) ----------------
__global__ void k_hist(const int* __restrict__ base_ids, int* __restrict__ wh) {
  int e = blockIdx.x * 256 + threadIdx.x;
  int b = base_ids[e];
  int gw = (blockIdx.x << 2) + (threadIdx.x >> 6);
  int lane = threadIdx.x & 63;
  #pragma unroll 1
  for (int t = 0; t < T_N; ++t) {
    unsigned long long m = __ballot(b == t);
    if (lane == 0) wh[(t << 10) + gw] = __popcll(m);
  }
}

__global__ void k_prefix(const int* __restrict__ wh, int* __restrict__ wb,
                         int* __restrict__ cnt) {
  int w = threadIdx.x >> 6;           // 9 waves, one per type
  int lane = threadIdx.x & 63;
  int run = 0;
  #pragma unroll 1
  for (int c = 0; c < 16; ++c) {
    int i = (c << 6) + lane;
    int v = wh[(w << 10) + i];
    int orig = v;
    #pragma unroll
    for (int off = 1; off < 64; off <<= 1) {
      int n2 = __shfl_up(v, off, 64);
      if (lane >= off) v += n2;
    }
    wb[(w << 10) + i] = run + v - orig;  // exclusive base for this wave-slot
    run += __shfl(v, 63, 64);
  }
  if (lane == 0) cnt[w] = run;
}

__global__ void k_scatter(const int* __restrict__ base_ids,
                          const int* __restrict__ wb, int* __restrict__ idx) {
  int e = blockIdx.x * 256 + threadIdx.x;
  int b = base_ids[e];
  int gw = (blockIdx.x << 2) + (threadIdx.x >> 6);
  int lane = threadIdx.x & 63;
  unsigned long long lanebit = 1ull << lane;
  #pragma unroll 1
  for (int t = 0; t < T_N; ++t) {
    unsigned long long m = __ballot(b == t);
    if (b == t) {
      int pos = wb[(t << 10) + gw] + __popcll(m & (lanebit - 1ull));
      idx[t * E_N + pos] = e;
    }
  }
}

// ------- embed/bias projections: ABc[ty][sr] = te@Wf0 + se@Wf1; D2b[t] = b2@Wf2 + bf -------
__global__ __launch_bounds__(256) void k_embed(
    const float* __restrict__ te, const float* __restrict__ se,
    const float* __restrict__ b2, const float* __restrict__ Wf,
    const float* __restrict__ bfv,
    float* __restrict__ ABc, float* __restrict__ D2b) {
  int b = blockIdx.x, d = threadIdx.x;
  if (b < 56) {
    int ty = b >> 2, sr = b & 3;
    const float* t0 = te + ty * 256;
    const float* s0 = se + sr * 256;
    float acc = 0.f;
    #pragma unroll 8
    for (int k = 0; k < 256; ++k) acc = fmaf(t0[k], Wf[(k << 8) + d], acc);
    #pragma unroll 8
    for (int k = 0; k < 256; ++k) acc = fmaf(s0[k], Wf[((256 + k) << 8) + d], acc);
    ABc[(b << 8) + d] = acc;
  } else {
    int t = b - 56;
    const float* bp = b2 + t * 256;
    float acc = bfv[d];
    #pragma unroll 8
    for (int k = 0; k < 256; ++k) acc = fmaf(bp[k], Wf[((512 + k) << 8) + d], acc);
    D2b[(t << 8) + d] = acc;
  }
}

// ------- C[t] = W2[t] @ Wf2, fp32 accumulate, packed bf16 out in B-frag order -------
// Cb[t][j>>3][d][j&7], so a lane's 8 consecutive k(=j) for col d is one 16B load.
__global__ __launch_bounds__(256) void k_C(
    const float* __restrict__ W2, const float* __restrict__ Wf,
    unsigned short* __restrict__ Cb) {
  int t = blockIdx.y;
  int j0 = blockIdx.x * 4;
  int d = threadIdx.x;
  __shared__ float w2s[4][256];
  for (int i = threadIdx.x; i < 4 * 256; i += 256)
    w2s[i >> 8][i & 255] = W2[t * 65536 + (j0 + (i >> 8)) * 256 + (i & 255)];
  __syncthreads();
  float acc[4] = {0.f, 0.f, 0.f, 0.f};
  #pragma unroll 8
  for (int k = 0; k < 256; ++k) {
    float wv = Wf[((512 + k) << 8) + d];
    #pragma unroll
    for (int jj = 0; jj < 4; ++jj) acc[jj] = fmaf(w2s[jj][k], wv, acc[jj]);
  }
  unsigned short* CbT = Cb + (size_t)t * 65536;
  #pragma unroll
  for (int jj = 0; jj < 4; ++jj) {
    int j = j0 + jj;
    CbT[(((j >> 3) << 8) + d) * 8 + (j & 7)] = f2bf(acc[jj]);
  }
}

// ---------------- main grouped GEMM via MFMA: out = relu(h @ C[t] + biases) ----------------
__global__ __launch_bounds__(256, 4) void edge_gemm(
    const int* __restrict__ cnt, const int* __restrict__ idxArr,
    const int* __restrict__ type_ids, const int* __restrict__ source_ids,
    const float* __restrict__ params,
    const float* __restrict__ W1, const float* __restrict__ b1,
    const unsigned short* __restrict__ Cb, const float* __restrict__ ABc,
    const float* __restrict__ D2b, float* __restrict__ out) {
  int t = blockIdx.y;
  int n = cnt[t];
  int m0 = blockIdx.x * 64;
  if (m0 >= n) return;

  __shared__ unsigned short hb[64 * 256];  // 32 KB, row-major [m][k], XOR-swizzled
  __shared__ int eidx[64];
  __shared__ int etyp[64];
  __shared__ int esrc[64];
  __shared__ float4 xs[64];

  int tid = threadIdx.x;
  if (tid < 64) {
    int m = m0 + tid;
    int mc = (m < n) ? m : (n - 1);
    int e = idxArr[(size_t)t * E_N + mc];
    eidx[tid] = e;
    etyp[tid] = type_ids[e];
    esrc[tid] = source_ids[e];
    float4 pr = *(const float4*)(params + (size_t)e * 4);
    float4 x;
    x.x = pr.x / SCALES_C[t][0];
    x.y = pr.y / SCALES_C[t][1];
    x.z = pr.z / SCALES_C[t][2];
    x.w = pr.w / SCALES_C[t][3];
    xs[tid] = x;
  }
  __syncthreads();

  // h[m][d] = relu(x[m].W1[t][:,d] + b1[t][d]), bf16 into swizzled LDS
  {
    int d = tid;
    const float* W1t = W1 + t * 1024;
    float w0 = W1t[d], w1 = W1t[256 + d], w2 = W1t[512 + d], w3 = W1t[768 + d];
    float b1d = b1[t * 256 + d];
    int dbyte = d << 1;
    #pragma unroll 4
    for (int m = 0; m < 64; ++m) {
      float4 x = xs[m];
      float h = fmaf(x.x, w0, fmaf(x.y, w1, fmaf(x.z, w2, fmaf(x.w, w3, b1d))));
      h = fmaxf(h, 0.f);
      int off = (m << 9) + (dbyte ^ ((m & 7) << 4));
      hb[off >> 1] = f2bf(h);
    }
  }
  __syncthreads();

  int lane = tid & 63;
  int w = tid >> 6;
  int l15 = lane & 15;
  int l4 = lane >> 4;

  f32x4 acc[4][4];
  #pragma unroll
  for (int i = 0; i < 4; ++i)
    #pragma unroll
    for (int j = 0; j < 4; ++j) acc[i][j] = (f32x4){0.f, 0.f, 0.f, 0.f};

  const unsigned short* CbT = Cb + (size_t)t * 65536;

  #pragma unroll 1
  for (int s = 0; s < 8; ++s) {
    bf16x8 bfr[4];
    #pragma unroll
    for (int nn = 0; nn < 4; ++nn) {
      int koct = (s << 2) + l4;
      int d = (w << 6) + (nn << 4) + l15;
      U8 u;
      u.u = *(const ushort8*)(CbT + (size_t)((koct << 8) + d) * 8);
      bfr[nn] = u.b;
    }
    #pragma unroll
    for (int mt = 0; mt < 4; ++mt) {
      int row = (mt << 4) + l15;
      int byte = (row << 9) + ((((s << 6) + (l4 << 4))) ^ ((row & 7) << 4));
      U8 a;
      a.u = *(const ushort8*)((const char*)hb + byte);
      #pragma unroll
      for (int nn = 0; nn < 4; ++nn)
        acc[mt][nn] = __builtin_amdgcn_mfma_f32_16x16x32_bf16(a.b, bfr[nn], acc[mt][nn], 0, 0, 0);
    }
  }

  // epilogue: + ABc[type][src] + D2b[t], relu, store (64B segments per 16 lanes)
  int dl = (w << 6) + l15;
  float d2v[4];
  #pragma unroll
  for (int nn = 0; nn < 4; ++nn) d2v[nn] = D2b[(t << 8) + dl + (nn << 4)];
  int rgrp = l4 << 2;
  #pragma unroll
  for (int mt = 0; mt < 4; ++mt) {
    #pragma unroll
    for (int r = 0; r < 4; ++r) {
      int mrow = (mt << 4) + rgrp + r;
      if (m0 + mrow < n) {
        int e = eidx[mrow];
        const float* abp = ABc + (size_t)(((etyp[mrow] << 2) + esrc[mrow]) << 8) + dl;
        float* op = out + (size_t)e * 256 + dl;
        #pragma unroll
        for (int nn = 0; nn < 4; ++nn) {
          float v = acc[mt][nn][r] + abp[nn << 4] + d2v[nn];
          op[nn << 4] = fmaxf(v, 0.f);
        }
      }
    }
  }
}

extern "C" void kernel_launch(void* const* d_in, const int* in_sizes, int n_in,
                              void* d_out, int out_size, void* d_ws, size_t ws_size,
                              hipStream_t stream) {
  const int*   type_ids   = (const int*)  d_in[0];
  const int*   source_ids = (const int*)  d_in[1];
  const int*   base_ids   = (const int*)  d_in[2];
  const float* params     = (const float*)d_in[3];
  const float* type_embed = (const float*)d_in[4];
  const float* src_embed  = (const float*)d_in[5];
  const float* W1         = (const float*)d_in[6];
  const float* b1         = (const float*)d_in[7];
  const float* W2         = (const float*)d_in[8];
  const float* b2         = (const float*)d_in[9];
  const float* Wf         = (const float*)d_in[10];
  const float* bfv        = (const float*)d_in[11];
  float* out = (float*)d_out;

  if (ws_size < WS_NEED_BYTES) return;

  float* wsf = (float*)d_ws;
  unsigned short* Cb = (unsigned short*)(wsf + OFF_CB);
  float* ABc = wsf + OFF_ABC;
  float* D2b = wsf + OFF_D2;
  int*   wh  = (int*)(wsf + OFF_WH);
  int*   wb  = (int*)(wsf + OFF_WB);
  int*   idx = (int*)(wsf + OFF_IDX);
  int*   cnt = wb + 9 * 1024 - 16;  // reuse tail of wb? no — keep separate:
  // use last 16 ints of wh region? wh is fully used. Put cnt in idx tail? idx fully used.
  // Allocate cnt right after D2b region inside ABC padding: D2b ends at OFF_WH; use wh? No.
  // Simplest: carve 16 ints from the front of wb is wrong too. Use static offset:
  cnt = (int*)(wsf + OFF_WH) - 16;  // 16 ints just before wh, inside unused pad? Not safe.

  // --- proper: place cnt after idx (idx ends at 329984+589824 = 919808 floats) ---
  cnt = (int*)(wsf + 919808);

  k_hist<<<E_N / 256, 256, 0, stream>>>(base_ids, wh);
  k_prefix<<<1, 576, 0, stream>>>(wh, wb, cnt);
  k_scatter<<<E_N / 256, 256, 0, stream>>>(base_ids, wb, idx);
  k_embed<<<65, 256, 0, stream>>>(type_embed, src_embed, b2, Wf, bfv, ABc, D2b);
  k_C<<<dim3(64, T_N), 256, 0, stream>>>(W2, Wf, Cb);
  edge_gemm<<<dim3(E_N / 64, T_N), 256, 0, stream>>>(
      cnt, idx, type_ids, source_ids, params, W1, b1, Cb, ABc, D2b, out);
}

// Round 3
// 66.665 us; speedup vs baseline: 4.1294x; 1.3274x over previous
//
#include <hip/hip_runtime.h>

#define E_N 65536
#define D_N 256
#define T_N 9

typedef __bf16 bf16x8 __attribute__((ext_vector_type(8)));
typedef float f32x4 __attribute__((ext_vector_type(4)));
typedef unsigned short ushort8 __attribute__((ext_vector_type(8)));
union U8 { ushort8 u; bf16x8 b; };

// ---------------- ws layout (float offsets) ----------------
#define OFF_CB   0          // 9*256*256 ushort = 294912 floats (bf16 packed C)
#define OFF_ABC  294912     // 56*256 floats
#define OFF_D2   309248     // 9*256 floats
#define OFF_BH   311552     // 9*256 ints (per-block histograms)
#define OFF_CNT  313856     // 16 ints
#define OFF_IDX  313872     // 9*65536 ints -> ends at 903696 floats (3.61 MB)
#define WS_NEED_BYTES ((size_t)(313872 + 589824) * 4)

__device__ __constant__ float SCALES_C[9][4] = {
  {1.f,    1e-6f, 1.f,  1.f},
  {1.f,    1e-6f, 1.f,  1.f},
  {1.f,    1.f,   1.f,  1.f},
  {1e3f,   1.f,   1.f,  1.f},
  {1e-12f, 1.f,   1.f,  1.f},
  {1e-9f,  1.f,   1.f,  1.f},
  {1.f,    1.f,   1.f,  1.f},
  {1e-3f,  1e-3f, 1.f,  1.f},
  {1.f,    1.f,   1e9f, 1.f},
};

__device__ inline unsigned short f2bf(float f) {
  unsigned int u = __float_as_uint(f);
  unsigned int r = (u + 0x7FFFu + ((u >> 16) & 1u)) >> 16;
  return (unsigned short)r;
}

// ============ fused prep: blocks [0,256) hist, [256,321) embed, [321,897) C ============
__global__ __launch_bounds__(256) void k_prep(
    const int* __restrict__ base_ids,
    const float* __restrict__ te, const float* __restrict__ se,
    const float* __restrict__ b2, const float* __restrict__ Wf,
    const float* __restrict__ bfv, const float* __restrict__ W2,
    int* __restrict__ bh, int* __restrict__ cnt,
    float* __restrict__ ABc, float* __restrict__ D2b,
    unsigned short* __restrict__ Cb) {
  int b = blockIdx.x;
  int tid = threadIdx.x;

  if (b < 256) {
    // ---- per-block histogram ----
    __shared__ int ph[9][4];
    int e = (b << 8) + tid;
    int bt = base_ids[e];
    int w = tid >> 6, lane = tid & 63;
    #pragma unroll 1
    for (int t = 0; t < T_N; ++t) {
      unsigned long long m = __ballot(bt == t);
      if (lane == 0) ph[t][w] = __popcll(m);
    }
    __syncthreads();
    if (tid < T_N) {
      int s = ph[tid][0] + ph[tid][1] + ph[tid][2] + ph[tid][3];
      bh[(tid << 8) + b] = s;
      atomicAdd(&cnt[tid], s);
    }
  } else if (b < 321) {
    // ---- embed/bias projections ----
    int bb = b - 256, d = tid;
    if (bb < 56) {
      int ty = bb >> 2, sr = bb & 3;
      const float* t0 = te + ty * 256;
      const float* s0 = se + sr * 256;
      float acc = 0.f;
      #pragma unroll 8
      for (int k = 0; k < 256; ++k) acc = fmaf(t0[k], Wf[(k << 8) + d], acc);
      #pragma unroll 8
      for (int k = 0; k < 256; ++k) acc = fmaf(s0[k], Wf[((256 + k) << 8) + d], acc);
      ABc[(bb << 8) + d] = acc;
    } else {
      int t = bb - 56;
      const float* bp = b2 + t * 256;
      float acc = bfv[d];
      #pragma unroll 8
      for (int k = 0; k < 256; ++k) acc = fmaf(bp[k], Wf[((512 + k) << 8) + d], acc);
      D2b[(t << 8) + d] = acc;
    }
  } else {
    // ---- C[t] = W2[t] @ Wf2, bf16 packed in B-frag order ----
    int cb = b - 321;
    int t = cb >> 6;
    int j0 = (cb & 63) << 2;
    int d = tid;
    __shared__ float w2s[4][256];
    for (int i = tid; i < 4 * 256; i += 256)
      w2s[i >> 8][i & 255] = W2[t * 65536 + (j0 + (i >> 8)) * 256 + (i & 255)];
    __syncthreads();
    float acc[4] = {0.f, 0.f, 0.f, 0.f};
    #pragma unroll 8
    for (int k = 0; k < 256; ++k) {
      float wv = Wf[((512 + k) << 8) + d];
      #pragma unroll
      for (int jj = 0; jj < 4; ++jj) acc[jj] = fmaf(w2s[jj][k], wv, acc[jj]);
    }
    unsigned short* CbT = Cb + (size_t)t * 65536;
    #pragma unroll
    for (int jj = 0; jj < 4; ++jj) {
      int j = j0 + jj;
      CbT[(((j >> 3) << 8) + d) * 8 + (j & 7)] = f2bf(acc[jj]);
    }
  }
}

// ============ scatter with self-computed prefix (no serial prefix kernel) ============
__global__ __launch_bounds__(256) void k_scatter(
    const int* __restrict__ base_ids, const int* __restrict__ bh,
    int* __restrict__ idx) {
  int g = blockIdx.x;
  int tid = threadIdx.x;
  int w = tid >> 6, lane = tid & 63;
  __shared__ int sph[9][4];    // per-wave popcounts -> exclusive offsets
  __shared__ int redw[9][4];   // per-wave reduction partials
  __shared__ int sbase[9];     // global exclusive base per type

  int e = (g << 8) + tid;
  int bt = base_ids[e];
  unsigned long long lanebit = 1ull << lane;

  #pragma unroll 1
  for (int t = 0; t < T_N; ++t) {
    unsigned long long m = __ballot(bt == t);
    if (lane == 0) sph[t][w] = __popcll(m);
  }

  // base[t] = sum over blocks i<g of bh[t][i]
  int v[9];
  #pragma unroll
  for (int t = 0; t < T_N; ++t) v[t] = (tid < g) ? bh[(t << 8) + tid] : 0;
  #pragma unroll
  for (int off = 32; off >= 1; off >>= 1) {
    #pragma unroll
    for (int t = 0; t < T_N; ++t) v[t] += __shfl_xor(v[t], off, 64);
  }
  if (lane == 0) {
    #pragma unroll
    for (int t = 0; t < T_N; ++t) redw[t][w] = v[t];
  }
  __syncthreads();
  if (tid < T_N) {
    sbase[tid] = redw[tid][0] + redw[tid][1] + redw[tid][2] + redw[tid][3];
    int o = 0;
    #pragma unroll
    for (int ww = 0; ww < 4; ++ww) { int tmp = sph[tid][ww]; sph[tid][ww] = o; o += tmp; }
  }
  __syncthreads();

  #pragma unroll 1
  for (int t = 0; t < T_N; ++t) {
    unsigned long long m = __ballot(bt == t);
    if (bt == t) {
      int pos = sbase[t] + sph[t][w] + __popcll(m & (lanebit - 1ull));
      idx[t * E_N + pos] = e;
    }
  }
}

// ============ main grouped GEMM via MFMA ============
__global__ __launch_bounds__(256, 4) void edge_gemm(
    const int* __restrict__ cnt, const int* __restrict__ idxArr,
    const int* __restrict__ type_ids, const int* __restrict__ source_ids,
    const float* __restrict__ params,
    const float* __restrict__ W1, const float* __restrict__ b1,
    const unsigned short* __restrict__ Cb, const float* __restrict__ ABc,
    const float* __restrict__ D2b, float* __restrict__ out) {
  // derive (t, m0) from cnt cumsum
  int b = blockIdx.x;
  int t = -1, m0 = 0, n = 0;
  {
    int acc = 0;
    #pragma unroll
    for (int tt = 0; tt < T_N; ++tt) {
      int c = cnt[tt];
      int nb = (c + 63) >> 6;
      if (t < 0 && b < acc + nb) { t = tt; m0 = (b - acc) << 6; n = c; }
      acc += nb;
    }
  }
  if (t < 0) return;

  __shared__ unsigned short hb[64 * 256];  // 32 KB, [m][k] bf16, XOR-swizzled
  __shared__ int eidx[64];
  __shared__ int etyp[64];
  __shared__ int esrc[64];
  __shared__ float4 xs[64];

  int tid = threadIdx.x;
  if (tid < 64) {
    int m = m0 + tid;
    int mc = (m < n) ? m : (n - 1);
    int e = idxArr[(size_t)t * E_N + mc];
    eidx[tid] = e;
    etyp[tid] = type_ids[e];
    esrc[tid] = source_ids[e];
    float4 pr = *(const float4*)(params + (size_t)e * 4);
    float4 x;
    x.x = pr.x / SCALES_C[t][0];
    x.y = pr.y / SCALES_C[t][1];
    x.z = pr.z / SCALES_C[t][2];
    x.w = pr.w / SCALES_C[t][3];
    xs[tid] = x;
  }
  __syncthreads();

  {
    int d = tid;
    const float* W1t = W1 + t * 1024;
    float w0 = W1t[d], w1 = W1t[256 + d], w2 = W1t[512 + d], w3 = W1t[768 + d];
    float b1d = b1[t * 256 + d];
    int dbyte = d << 1;
    #pragma unroll 4
    for (int m = 0; m < 64; ++m) {
      float4 x = xs[m];
      float h = fmaf(x.x, w0, fmaf(x.y, w1, fmaf(x.z, w2, fmaf(x.w, w3, b1d))));
      h = fmaxf(h, 0.f);
      int off = (m << 9) + (dbyte ^ ((m & 7) << 4));
      hb[off >> 1] = f2bf(h);
    }
  }
  __syncthreads();

  int lane = tid & 63;
  int w = tid >> 6;
  int l15 = lane & 15;
  int l4 = lane >> 4;

  f32x4 acc[4][4];
  #pragma unroll
  for (int i = 0; i < 4; ++i)
    #pragma unroll
    for (int j = 0; j < 4; ++j) acc[i][j] = (f32x4){0.f, 0.f, 0.f, 0.f};

  const unsigned short* CbT = Cb + (size_t)t * 65536;

  #pragma unroll 1
  for (int s = 0; s < 8; ++s) {
    bf16x8 bfr[4];
    #pragma unroll
    for (int nn = 0; nn < 4; ++nn) {
      int koct = (s << 2) + l4;
      int d = (w << 6) + (nn << 4) + l15;
      U8 u;
      u.u = *(const ushort8*)(CbT + (size_t)((koct << 8) + d) * 8);
      bfr[nn] = u.b;
    }
    #pragma unroll
    for (int mt = 0; mt < 4; ++mt) {
      int row = (mt << 4) + l15;
      int byte = (row << 9) + ((((s << 6) + (l4 << 4))) ^ ((row & 7) << 4));
      U8 a;
      a.u = *(const ushort8*)((const char*)hb + byte);
      #pragma unroll
      for (int nn = 0; nn < 4; ++nn)
        acc[mt][nn] = __builtin_amdgcn_mfma_f32_16x16x32_bf16(a.b, bfr[nn], acc[mt][nn], 0, 0, 0);
    }
  }

  int dl = (w << 6) + l15;
  float d2v[4];
  #pragma unroll
  for (int nn = 0; nn < 4; ++nn) d2v[nn] = D2b[(t << 8) + dl + (nn << 4)];
  int rgrp = l4 << 2;
  #pragma unroll
  for (int mt = 0; mt < 4; ++mt) {
    #pragma unroll
    for (int r = 0; r < 4; ++r) {
      int mrow = (mt << 4) + rgrp + r;
      if (m0 + mrow < n) {
        int e = eidx[mrow];
        const float* abp = ABc + (size_t)(((etyp[mrow] << 2) + esrc[mrow]) << 8) + dl;
        float* op = out + (size_t)e * 256 + dl;
        #pragma unroll
        for (int nn = 0; nn < 4; ++nn) {
          float v = acc[mt][nn][r] + abp[nn << 4] + d2v[nn];
          op[nn << 4] = fmaxf(v, 0.f);
        }
      }
    }
  }
}

extern "C" void kernel_launch(void* const* d_in, const int* in_sizes, int n_in,
                              void* d_out, int out_size, void* d_ws, size_t ws_size,
                              hipStream_t stream) {
  const int*   type_ids   = (const int*)  d_in[0];
  const int*   source_ids = (const int*)  d_in[1];
  const int*   base_ids   = (const int*)  d_in[2];
  const float* params     = (const float*)d_in[3];
  const float* type_embed = (const float*)d_in[4];
  const float* src_embed  = (const float*)d_in[5];
  const float* W1         = (const float*)d_in[6];
  const float* b1         = (const float*)d_in[7];
  const float* W2         = (const float*)d_in[8];
  const float* b2         = (const float*)d_in[9];
  const float* Wf         = (const float*)d_in[10];
  const float* bfv        = (const float*)d_in[11];
  float* out = (float*)d_out;

  if (ws_size < WS_NEED_BYTES) return;

  float* wsf = (float*)d_ws;
  unsigned short* Cb = (unsigned short*)(wsf + OFF_CB);
  float* ABc = wsf + OFF_ABC;
  float* D2b = wsf + OFF_D2;
  int*   bh  = (int*)(wsf + OFF_BH);
  int*   cnt = (int*)(wsf + OFF_CNT);
  int*   idx = (int*)(wsf + OFF_IDX);

  hipMemsetAsync(cnt, 0, 16 * sizeof(int), stream);
  k_prep<<<897, 256, 0, stream>>>(base_ids, type_embed, src_embed, b2, Wf, bfv,
                                  W2, bh, cnt, ABc, D2b, Cb);
  k_scatter<<<256, 256, 0, stream>>>(base_ids, bh, idx);
  edge_gemm<<<1033, 256, 0, stream>>>(cnt, idx, type_ids, source_ids, params,
                                      W1, b1, Cb, ABc, D2b, out);
}

// Round 4
// 66.370 us; speedup vs baseline: 4.1478x; 1.0045x over previous
//
#include <hip/hip_runtime.h>

#define E_N 65536
#define T_N 9

typedef __bf16 bf16x8 __attribute__((ext_vector_type(8)));
typedef float f32x4 __attribute__((ext_vector_type(4)));
typedef unsigned short ushort8 __attribute__((ext_vector_type(8)));
union U8 { ushort8 u; bf16x8 b; };

// ---------------- ws layout (float offsets) ----------------
#define OFF_CB   0          // 9*256*256 ushort = 294912 floats (bf16 packed C)
#define OFF_ABC  294912     // 56*256 floats
#define OFF_D2   309248     // 9*256 floats
#define OFF_BH   311552     // 9*256 ints (per-block histograms)
#define OFF_CNT  313856     // 16 ints
#define OFF_IDX  313872     // 9*65536 ints
#define WS_NEED_BYTES ((size_t)(313872 + 589824) * 4)

__device__ __constant__ float SCALES_C[9][4] = {
  {1.f,    1e-6f, 1.f,  1.f},
  {1.f,    1e-6f, 1.f,  1.f},
  {1.f,    1.f,   1.f,  1.f},
  {1e3f,   1.f,   1.f,  1.f},
  {1e-12f, 1.f,   1.f,  1.f},
  {1e-9f,  1.f,   1.f,  1.f},
  {1.f,    1.f,   1.f,  1.f},
  {1e-3f,  1e-3f, 1.f,  1.f},
  {1.f,    1.f,   1e9f, 1.f},
};

__device__ inline unsigned short f2bf(float f) {
  unsigned int u = __float_as_uint(f);
  unsigned int r = (u + 0x7FFFu + ((u >> 16) & 1u)) >> 16;
  return (unsigned short)r;
}

// ============ K1: blocks [0,256) per-block hist, [256,321) embed/bias projections ============
__global__ __launch_bounds__(256) void k_hist_embed(
    const int* __restrict__ base_ids,
    const float* __restrict__ te, const float* __restrict__ se,
    const float* __restrict__ b2, const float* __restrict__ Wf,
    const float* __restrict__ bfv,
    int* __restrict__ bh, float* __restrict__ ABc, float* __restrict__ D2b) {
  int b = blockIdx.x;
  int tid = threadIdx.x;

  if (b < 256) {
    __shared__ int ph[9][4];
    int e = (b << 8) + tid;
    int bt = base_ids[e];
    int w = tid >> 6, lane = tid & 63;
    #pragma unroll 1
    for (int t = 0; t < T_N; ++t) {
      unsigned long long m = __ballot(bt == t);
      if (lane == 0) ph[t][w] = __popcll(m);
    }
    __syncthreads();
    if (tid < T_N)
      bh[(tid << 8) + b] = ph[tid][0] + ph[tid][1] + ph[tid][2] + ph[tid][3];
  } else {
    int bb = b - 256, d = tid;
    if (bb < 56) {
      int ty = bb >> 2, sr = bb & 3;
      const float* t0 = te + ty * 256;
      const float* s0 = se + sr * 256;
      float a0 = 0.f, a1 = 0.f, a2 = 0.f, a3 = 0.f;
      #pragma unroll 4
      for (int k = 0; k < 256; k += 4) {
        a0 = fmaf(t0[k + 0], Wf[((k + 0) << 8) + d], a0);
        a1 = fmaf(t0[k + 1], Wf[((k + 1) << 8) + d], a1);
        a2 = fmaf(t0[k + 2], Wf[((k + 2) << 8) + d], a2);
        a3 = fmaf(t0[k + 3], Wf[((k + 3) << 8) + d], a3);
      }
      #pragma unroll 4
      for (int k = 0; k < 256; k += 4) {
        a0 = fmaf(s0[k + 0], Wf[((256 + k + 0) << 8) + d], a0);
        a1 = fmaf(s0[k + 1], Wf[((256 + k + 1) << 8) + d], a1);
        a2 = fmaf(s0[k + 2], Wf[((256 + k + 2) << 8) + d], a2);
        a3 = fmaf(s0[k + 3], Wf[((256 + k + 3) << 8) + d], a3);
      }
      ABc[(bb << 8) + d] = (a0 + a1) + (a2 + a3);
    } else {
      int t = bb - 56;
      const float* bp = b2 + t * 256;
      float a0 = bfv[d], a1 = 0.f, a2 = 0.f, a3 = 0.f;
      #pragma unroll 4
      for (int k = 0; k < 256; k += 4) {
        a0 = fmaf(bp[k + 0], Wf[((512 + k + 0) << 8) + d], a0);
        a1 = fmaf(bp[k + 1], Wf[((512 + k + 1) << 8) + d], a1);
        a2 = fmaf(bp[k + 2], Wf[((512 + k + 2) << 8) + d], a2);
        a3 = fmaf(bp[k + 3], Wf[((512 + k + 3) << 8) + d], a3);
      }
      D2b[(t << 8) + d] = (a0 + a1) + (a2 + a3);
    }
  }
}

// ============ K2: blocks [0,288) C = W2@Wf2 (bf16 packed); [288,544) scatter ============
__global__ __launch_bounds__(256) void k_c_scatter(
    const float* __restrict__ W2, const float* __restrict__ Wf,
    const int* __restrict__ base_ids, const int* __restrict__ type_ids,
    const int* __restrict__ source_ids, const int* __restrict__ bh,
    unsigned short* __restrict__ Cb, int* __restrict__ idx,
    int* __restrict__ cnt) {
  int b = blockIdx.x;
  int tid = threadIdx.x;

  if (b < 288) {
    // ---- C[t] = W2[t] @ Wf2, fp32 accum, bf16 packed in B-frag order ----
    int t = b >> 5;
    int j0 = (b & 31) << 3;      // 8 rows per block
    __shared__ float w2s[8][256];
    for (int i = tid; i < 2048; i += 256)
      w2s[i >> 8][i & 255] = W2[t * 65536 + (j0 + (i >> 8)) * 256 + (i & 255)];
    __syncthreads();
    int dg = (tid & 63) << 2;    // 4 consecutive d
    int jg = (tid >> 6) << 1;    // 2 consecutive j (within the 8)
    f32x4 acc0 = {0.f, 0.f, 0.f, 0.f}, acc1 = {0.f, 0.f, 0.f, 0.f};
    #pragma unroll 4
    for (int k = 0; k < 256; ++k) {
      f32x4 wv = *(const f32x4*)&Wf[((512 + k) << 8) + dg];
      float a0 = w2s[jg][k], a1 = w2s[jg + 1][k];
      acc0.x = fmaf(a0, wv.x, acc0.x); acc0.y = fmaf(a0, wv.y, acc0.y);
      acc0.z = fmaf(a0, wv.z, acc0.z); acc0.w = fmaf(a0, wv.w, acc0.w);
      acc1.x = fmaf(a1, wv.x, acc1.x); acc1.y = fmaf(a1, wv.y, acc1.y);
      acc1.z = fmaf(a1, wv.z, acc1.z); acc1.w = fmaf(a1, wv.w, acc1.w);
    }
    unsigned short* CbT = Cb + (size_t)t * 65536;
    int j = j0 + jg;             // even; j and j+1 share the k-oct
    #pragma unroll
    for (int c = 0; c < 4; ++c) {
      int d = dg + c;
      unsigned int pk = (unsigned int)f2bf((c == 0) ? acc0.x : (c == 1) ? acc0.y : (c == 2) ? acc0.z : acc0.w)
                      | ((unsigned int)f2bf((c == 0) ? acc1.x : (c == 1) ? acc1.y : (c == 2) ? acc1.z : acc1.w) << 16);
      *(unsigned int*)&CbT[(((j >> 3) << 8) + d) * 8 + (j & 7)] = pk;
    }
  } else {
    // ---- scatter with self-computed prefix; block g==255 writes cnt ----
    int g = b - 288;
    int w = tid >> 6, lane = tid & 63;
    __shared__ int sph[9][4];
    __shared__ int redw[9][4];
    __shared__ int sbase[9];

    int e = (g << 8) + tid;
    int bt = base_ids[e];
    int pk = e | (type_ids[e] << 16) | (source_ids[e] << 20);
    unsigned long long lanebit = 1ull << lane;

    #pragma unroll 1
    for (int t = 0; t < T_N; ++t) {
      unsigned long long m = __ballot(bt == t);
      if (lane == 0) sph[t][w] = __popcll(m);
    }

    int v[9];
    #pragma unroll
    for (int t = 0; t < T_N; ++t) v[t] = (tid < g) ? bh[(t << 8) + tid] : 0;
    #pragma unroll
    for (int off = 32; off >= 1; off >>= 1) {
      #pragma unroll
      for (int t = 0; t < T_N; ++t) v[t] += __shfl_xor(v[t], off, 64);
    }
    if (lane == 0) {
      #pragma unroll
      for (int t = 0; t < T_N; ++t) redw[t][w] = v[t];
    }
    __syncthreads();
    if (tid < T_N) {
      sbase[tid] = redw[tid][0] + redw[tid][1] + redw[tid][2] + redw[tid][3];
      int tot = sph[tid][0] + sph[tid][1] + sph[tid][2] + sph[tid][3];
      if (g == 255) cnt[tid] = sbase[tid] + tot;
      int o = 0;
      #pragma unroll
      for (int ww = 0; ww < 4; ++ww) { int tmp = sph[tid][ww]; sph[tid][ww] = o; o += tmp; }
    }
    __syncthreads();

    #pragma unroll 1
    for (int t = 0; t < T_N; ++t) {
      unsigned long long m = __ballot(bt == t);
      if (bt == t) {
        int pos = sbase[t] + sph[t][w] + __popcll(m & (lanebit - 1ull));
        idx[t * E_N + pos] = pk;
      }
    }
  }
}

// ============ K3: grouped GEMM via MFMA: out = relu(h @ C[t] + biases) ============
__global__ __launch_bounds__(256, 4) void edge_gemm(
    const int* __restrict__ cnt, const int* __restrict__ idxArr,
    const float* __restrict__ params,
    const float* __restrict__ W1, const float* __restrict__ b1,
    const unsigned short* __restrict__ Cb, const float* __restrict__ ABc,
    const float* __restrict__ D2b, float* __restrict__ out) {
  int b = blockIdx.x;
  int t = -1, m0 = 0, n = 0;
  {
    int acc = 0;
    #pragma unroll
    for (int tt = 0; tt < T_N; ++tt) {
      int c = cnt[tt];
      int nb = (c + 63) >> 6;
      if (t < 0 && b < acc + nb) { t = tt; m0 = (b - acc) << 6; n = c; }
      acc += nb;
    }
  }
  if (t < 0) return;

  __shared__ unsigned short hb[64 * 256];  // 32 KB; bf16 h (swizzled) then f32 rows (epilogue)
  __shared__ int eidx[64];                 // packed e|ty<<16|sr<<20
  __shared__ float4 xs[64];

  int tid = threadIdx.x;
  if (tid < 64) {
    int m = m0 + tid;
    int mc = (m < n) ? m : (n - 1);
    int pk = idxArr[(size_t)t * E_N + mc];
    eidx[tid] = pk;
    int e = pk & 0xFFFF;
    float4 pr = *(const float4*)(params + (size_t)e * 4);
    float4 x;
    x.x = pr.x / SCALES_C[t][0];
    x.y = pr.y / SCALES_C[t][1];
    x.z = pr.z / SCALES_C[t][2];
    x.w = pr.w / SCALES_C[t][3];
    xs[tid] = x;
  }
  __syncthreads();

  // h[m][d] = relu(x[m].W1[t][:,d] + b1[t][d]) -> bf16, XOR-swizzled rows
  {
    int d = tid;
    const float* W1t = W1 + t * 1024;
    float w0 = W1t[d], w1 = W1t[256 + d], w2 = W1t[512 + d], w3 = W1t[768 + d];
    float b1d = b1[t * 256 + d];
    int dbyte = d << 1;
    #pragma unroll 4
    for (int m = 0; m < 64; ++m) {
      float4 x = xs[m];
      float h = fmaf(x.x, w0, fmaf(x.y, w1, fmaf(x.z, w2, fmaf(x.w, w3, b1d))));
      h = fmaxf(h, 0.f);
      int off = (m << 9) + (dbyte ^ ((m & 7) << 4));
      hb[off >> 1] = f2bf(h);
    }
  }
  __syncthreads();

  int lane = tid & 63;
  int w = tid >> 6;
  int l15 = lane & 15;
  int l4 = lane >> 4;

  f32x4 acc[4][4];
  #pragma unroll
  for (int i = 0; i < 4; ++i)
    #pragma unroll
    for (int j = 0; j < 4; ++j) acc[i][j] = (f32x4){0.f, 0.f, 0.f, 0.f};

  const unsigned short* CbT = Cb + (size_t)t * 65536;

  #pragma unroll 1
  for (int s = 0; s < 8; ++s) {
    bf16x8 bfr[4];
    #pragma unroll
    for (int nn = 0; nn < 4; ++nn) {
      int koct = (s << 2) + l4;
      int d = (w << 6) + (nn << 4) + l15;
      U8 u;
      u.u = *(const ushort8*)(CbT + (size_t)((koct << 8) + d) * 8);
      bfr[nn] = u.b;
    }
    __builtin_amdgcn_s_setprio(1);
    #pragma unroll
    for (int mt = 0; mt < 4; ++mt) {
      int row = (mt << 4) + l15;
      int byte = (row << 9) + ((((s << 6) + (l4 << 4))) ^ ((row & 7) << 4));
      U8 a;
      a.u = *(const ushort8*)((const char*)hb + byte);
      #pragma unroll
      for (int nn = 0; nn < 4; ++nn)
        acc[mt][nn] = __builtin_amdgcn_mfma_f32_16x16x32_bf16(a.b, bfr[nn], acc[mt][nn], 0, 0, 0);
    }
    __builtin_amdgcn_s_setprio(0);
  }

  // ---- epilogue: transpose through LDS (hb dead), vectorized bias add + store ----
  float* fb = (float*)hb;                    // [32][256] f32 per pass
  const float* d2p = D2b + (t << 8);
  #pragma unroll
  for (int p = 0; p < 2; ++p) {
    __syncthreads();
    #pragma unroll
    for (int mh = 0; mh < 2; ++mh) {
      int mt = (p << 1) + mh;
      int lrb = (mh << 4) + (l4 << 2);
      #pragma unroll
      for (int nn = 0; nn < 4; ++nn) {
        int col = (w << 6) + (nn << 4) + l15;
        #pragma unroll
        for (int r = 0; r < 4; ++r) {
          int lr = lrb + r;
          fb[lr * 256 + (col ^ ((lr & 7) << 2))] = acc[mt][nn][r];
        }
      }
    }
    __syncthreads();
    int lr = tid >> 3;                       // 0..31
    int c8 = tid & 7;                        // 0..7
    int row_g = (p << 5) + lr;
    if (m0 + row_g < n) {
      int pk = eidx[row_g];
      int e = pk & 0xFFFF;
      int ty = (pk >> 16) & 15;
      int sr = (pk >> 20) & 3;
      const float* abp = ABc + (size_t)(((ty << 2) + sr) << 8);
      float* op = out + (size_t)e * 256;
      int sw = (lr & 7) << 2;
      #pragma unroll
      for (int v = 0; v < 8; ++v) {
        int col = (c8 << 2) + (v << 5);
        f32x4 vv = *(const f32x4*)&fb[lr * 256 + (col ^ sw)];
        f32x4 ab = *(const f32x4*)&abp[col];
        f32x4 d2 = *(const f32x4*)&d2p[col];
        f32x4 rr;
        rr.x = fmaxf(vv.x + ab.x + d2.x, 0.f);
        rr.y = fmaxf(vv.y + ab.y + d2.y, 0.f);
        rr.z = fmaxf(vv.z + ab.z + d2.z, 0.f);
        rr.w = fmaxf(vv.w + ab.w + d2.w, 0.f);
        *(f32x4*)&op[col] = rr;
      }
    }
  }
}

extern "C" void kernel_launch(void* const* d_in, const int* in_sizes, int n_in,
                              void* d_out, int out_size, void* d_ws, size_t ws_size,
                              hipStream_t stream) {
  const int*   type_ids   = (const int*)  d_in[0];
  const int*   source_ids = (const int*)  d_in[1];
  const int*   base_ids   = (const int*)  d_in[2];
  const float* params     = (const float*)d_in[3];
  const float* type_embed = (const float*)d_in[4];
  const float* src_embed  = (const float*)d_in[5];
  const float* W1         = (const float*)d_in[6];
  const float* b1         = (const float*)d_in[7];
  const float* W2         = (const float*)d_in[8];
  const float* b2         = (const float*)d_in[9];
  const float* Wf         = (const float*)d_in[10];
  const float* bfv        = (const float*)d_in[11];
  float* out = (float*)d_out;

  if (ws_size < WS_NEED_BYTES) return;

  float* wsf = (float*)d_ws;
  unsigned short* Cb = (unsigned short*)(wsf + OFF_CB);
  float* ABc = wsf + OFF_ABC;
  float* D2b = wsf + OFF_D2;
  int*   bh  = (int*)(wsf + OFF_BH);
  int*   cnt = (int*)(wsf + OFF_CNT);
  int*   idx = (int*)(wsf + OFF_IDX);

  k_hist_embed<<<321, 256, 0, stream>>>(base_ids, type_embed, src_embed, b2, Wf,
                                        bfv, bh, ABc, D2b);
  k_c_scatter<<<544, 256, 0, stream>>>(W2, Wf, base_ids, type_ids, source_ids,
                                       bh, Cb, idx, cnt);
  edge_gemm<<<1033, 256, 0, stream>>>(cnt, idx, params, W1, b1, Cb, ABc, D2b, out);
}